// Round 10
// baseline (246.069 us; speedup 1.0000x reference)
//
#include <hip/hip_runtime.h>
#include <math.h>

#define B_   4
#define S_   2048
#define H_   1024
#define NH   16
#define HD   64
#define T_   (B_ * S_)       // 8192 tokens
#define NCH  8               // kv S-chunks (256 rows each)

typedef unsigned short u16;
typedef __bf16 bf16x8 __attribute__((ext_vector_type(8)));
typedef float  f32x4  __attribute__((ext_vector_type(4)));

// ---------------------------------------------------------------------------
__device__ __forceinline__ float elu_k(float x) {
    return (x > 0.f ? x : (expf(x) - 1.f)) + 1.000001f;
}

__device__ __forceinline__ u16 f2bf(float x) {
    union { float f; unsigned int u; } v; v.f = x;
    unsigned int r = v.u + 0x7FFFu + ((v.u >> 16) & 1u);
    return (u16)(r >> 16);
}

__device__ __forceinline__ float bfl(unsigned int u) {
    union { unsigned int u; float f; } v; v.u = u << 16; return v.f;
}
__device__ __forceinline__ float bfh(unsigned int u) {
    union { unsigned int u; float f; } v; v.u = u & 0xFFFF0000u; return v.f;
}
__device__ __forceinline__ float bfu16(u16 x) {
    union { unsigned int u; float f; } v; v.u = (unsigned int)x << 16; return v.f;
}

// async global->LDS, 16 B/lane; LDS side uses lane0's base + lane*16,
// global side is per-lane.
__device__ __forceinline__ void async_load16(const u16* g, u16* l) {
    __builtin_amdgcn_global_load_lds(
        (const __attribute__((address_space(1))) void*)g,
        (__attribute__((address_space(3))) void*)l,
        16, 0, 0);
}

// ---------------------------------------------------------------------------
// Merged prologue: cvt_gate (blocks 0..8191) | pack_w (8192..9215) |
// prep (9216..9485).  Sections fully independent (disjoint reads/writes).
__global__ __launch_bounds__(256) void pre_kernel(
    const float* __restrict__ hs, const float* __restrict__ Wg,
    const float* __restrict__ bg, const float* __restrict__ Wq,
    const float* __restrict__ Wk, const float* __restrict__ Wv,
    const float* __restrict__ Wo, const float* __restrict__ decay,
    const float* __restrict__ gate, const float* __restrict__ bq,
    const float* __restrict__ bk, const float* __restrict__ bv,
    u16* __restrict__ hsb, float* __restrict__ gbuf, u16* __restrict__ Wt,
    float* __restrict__ coeff, float* __restrict__ cosT,
    float* __restrict__ sinT, float* __restrict__ bqkv) {
    __shared__ u16 tile[64][65];
    __shared__ float wsum[4];
    const int blk = blockIdx.x;
    const int tid = threadIdx.x;

    if (blk < T_) {
        // ---- cvt_gate: hs->bf16 + gate gemv, one block per token
        int t = blk;
        float4 f = ((const float4*)(hs + (size_t)t * H_))[tid];
        float4 w = ((const float4*)Wg)[tid];
        ushort4 u;
        u.x = f2bf(f.x); u.y = f2bf(f.y); u.z = f2bf(f.z); u.w = f2bf(f.w);
        ((ushort4*)(hsb + (size_t)t * H_))[tid] = u;
        float s = f.x * w.x + f.y * w.y + f.z * w.z + f.w * w.w;
#pragma unroll
        for (int off = 32; off > 0; off >>= 1) s += __shfl_down(s, off);
        if ((tid & 63) == 0) wsum[tid >> 6] = s;
        __syncthreads();
        if (tid == 0) {
            float tot = wsum[0] + wsum[1] + wsum[2] + wsum[3];
            gbuf[t] = 1.f / (1.f + expf(-(tot + bg[0])));
        }
    } else if (blk < T_ + 1024) {
        // ---- pack_w: Wt[w*1024 + n][k] = bf16(W_w[k][n])
        int idx = blk - T_;
        int wsel = idx >> 8, rem = idx & 255;
        int nt = (rem & 15) * 64, kt = (rem >> 4) * 64;
        const float* W = (wsel == 0) ? Wq : (wsel == 1) ? Wk :
                         (wsel == 2) ? Wv : Wo;
#pragma unroll
        for (int it = 0; it < 16; it++) {
            int i = it * 256 + tid;
            int kr = i >> 6, nc = i & 63;
            tile[kr][nc] = f2bf(W[(size_t)(kt + kr) * H_ + nt + nc]);
        }
        __syncthreads();
        size_t wbase = (size_t)wsel * H_;
#pragma unroll
        for (int it = 0; it < 16; it++) {
            int i = it * 256 + tid;
            int nr = i >> 6, kc = i & 63;
            Wt[(wbase + nt + nr) * H_ + kt + kc] = tile[kc][nr];
        }
    } else {
        // ---- prep: rope tables + packed bias + coeff
        int idx = (blk - (T_ + 1024)) * 256 + tid;
        if (idx < S_ * 32) {
            int s = idx >> 5, i = idx & 31;
            float inv = powf(10000.f, -(2.f * (float)i) / 64.f);
            float f = (float)s * inv;
            cosT[idx] = cosf(f);
            sinT[idx] = sinf(f);
        } else if (idx < S_ * 32 + 3072) {
            int i = idx - S_ * 32;
            bqkv[i] = (i < 1024) ? bq[i] : (i < 2048) ? bk[i - 1024]
                                                      : bv[i - 2048];
        } else if (idx == S_ * 32 + 3072) {
            float g0 = gate[0], g1 = gate[1], g2 = gate[2];
            float mx = fmaxf(g0, fmaxf(g1, g2));
            float e0 = expf(g0 - mx), e1 = expf(g1 - mx), e2 = expf(g2 - mx);
            float inv = 1.f / (e0 + e1 + e2);
            float es[3] = {e0, e1, e2};
            float c = 0.f;
            for (int m = 0; m < 3; m++) {
                float ds = 1.f / (1.f + expf(-decay[m]));
                c += es[m] * inv * (1.f - ds);
            }
            *coeff = c;
        }
    }
}

// ---------------------------------------------------------------------------
// GEMM core v7 (qkv): single barrier per K-tile, triple-buffered LDS.
// Measured R9: 76.6 us, MfmaUtil 28%, 0 bank conflicts.  Unchanged.

#define STAGE6(AST, BST)                                                      \
    {                                                                         \
        async_load16(pa0, &sAB[(AST) + wid * 2048 + lane * 8]);               \
        async_load16(pa1, &sAB[(AST) + wid * 2048 + 512 + lane * 8]);         \
        async_load16(pa2, &sAB[(AST) + wid * 2048 + 1024 + lane * 8]);        \
        async_load16(pa3, &sAB[(AST) + wid * 2048 + 1536 + lane * 8]);        \
        async_load16(pb0, &sAB[(BST) + wid * 1024 + lane * 8]);               \
        async_load16(pb1, &sAB[(BST) + wid * 1024 + 512 + lane * 8]);         \
        pa0 += 64; pa1 += 64; pa2 += 64; pa3 += 64; pb0 += 64; pb1 += 64;     \
    }

#define MFMA16(AV, BV)                                                        \
    __builtin_amdgcn_s_setprio(1);                                            \
    _Pragma("unroll")                                                         \
    for (int mi = 0; mi < 4; mi++)                                            \
        _Pragma("unroll")                                                     \
        for (int nj = 0; nj < 4; nj++)                                        \
            acc[mi][nj] = __builtin_amdgcn_mfma_f32_16x16x32_bf16(            \
                AV[mi], BV[nj], acc[mi][nj], 0, 0, 0);                        \
    __builtin_amdgcn_s_setprio(0);

#define KLOOP(A_, Bt_)                                                        \
    const u16* pa0 = A_ + (size_t)(bm + wid * 32 +  0 + ln8) * 1024 + scs8;   \
    const u16* pa1 = A_ + (size_t)(bm + wid * 32 +  8 + ln8) * 1024 + scs8;   \
    const u16* pa2 = A_ + (size_t)(bm + wid * 32 + 16 + ln8) * 1024 + scs8;   \
    const u16* pa3 = A_ + (size_t)(bm + wid * 32 + 24 + ln8) * 1024 + scs8;   \
    const u16* pb0 = Bt_ + (size_t)(bn + wid * 16 +  0 + ln8) * 1024 + scs8;  \
    const u16* pb1 = Bt_ + (size_t)(bn + wid * 16 +  8 + ln8) * 1024 + scs8;  \
    bf16x8 a0[4], b0[4], a1[4], b1[4];                                        \
    STAGE6(0, 49152)                        /* stage tile 0 -> buf0 */        \
    STAGE6(16384, 57344)                    /* stage tile 1 -> buf1 */        \
    asm volatile("s_waitcnt vmcnt(6)" ::: "memory");  /* tile0 landed */      \
    __builtin_amdgcn_s_barrier();                                             \
    _Pragma("unroll")                                                         \
    for (int n = 0; n < 16; ++n) {                                            \
        const int rdA = (n % 3) * 16384;                                      \
        const int rdB = 49152 + (n % 3) * 8192;                               \
        const int stA = ((n + 2) % 3) * 16384;                                \
        const int stB = 49152 + ((n + 2) % 3) * 8192;                         \
        const u16* Ab = &sAB[rdA + (wr * 64 + l15) * 64];                     \
        const u16* Bb = &sAB[rdB + (wc * 64 + l15) * 64];                     \
        _Pragma("unroll")                                                     \
        for (int mi = 0; mi < 4; mi++)                                        \
            a0[mi] = *(const bf16x8*)&Ab[mi * 1024 + sw0];                    \
        _Pragma("unroll")                                                     \
        for (int nj = 0; nj < 4; nj++)                                        \
            b0[nj] = *(const bf16x8*)&Bb[nj * 1024 + sw0];                    \
        __builtin_amdgcn_sched_barrier(0);                                    \
        _Pragma("unroll")                                                     \
        for (int mi = 0; mi < 4; mi++)                                        \
            a1[mi] = *(const bf16x8*)&Ab[mi * 1024 + sw1];                    \
        _Pragma("unroll")                                                     \
        for (int nj = 0; nj < 4; nj++)                                        \
            b1[nj] = *(const bf16x8*)&Bb[nj * 1024 + sw1];                    \
        __builtin_amdgcn_sched_barrier(0);                                    \
        if (n + 2 < 16) STAGE6(stA, stB)                                      \
        asm volatile("s_waitcnt lgkmcnt(8)" ::: "memory");                    \
        __builtin_amdgcn_sched_barrier(0);                                    \
        MFMA16(a0, b0)                                                        \
        __builtin_amdgcn_sched_barrier(0);                                    \
        asm volatile("s_waitcnt lgkmcnt(0)" ::: "memory");                    \
        __builtin_amdgcn_sched_barrier(0);                                    \
        MFMA16(a1, b1)                                                        \
        __builtin_amdgcn_sched_barrier(0);                                    \
        if (n < 14) {                                                         \
            asm volatile("s_waitcnt vmcnt(6)" ::: "memory");                  \
        } else if (n == 14) {                                                 \
            asm volatile("s_waitcnt vmcnt(0)" ::: "memory");                  \
        }                                                                     \
        asm volatile("" ::: "memory");                                        \
        __builtin_amdgcn_s_barrier();                                         \
    }

// R4-style GEMM core (gemm_out): BM=BN=128, 4 waves, 64 KiB dbuf,
// counted vmcnt(8), 2 blocks/CU.  Unchanged.
#define OSTAGE8(A_, Bt_, n_)                                                  \
    {                                                                         \
        const int dst = ((n_) & 1) * 8192;                                    \
        _Pragma("unroll")                                                     \
        for (int i = 0; i < 4; i++) {                                         \
            async_load16(&A_[(size_t)(bm + wid * 32 + i * 8 + ln8) * 1024 +   \
                             (n_) * 64 + scs8],                               \
                         &sAB[dst + wid * 2048 + i * 512 + lane * 8]);        \
            async_load16(&Bt_[(size_t)(bn + wid * 32 + i * 8 + ln8) * 1024 +  \
                              (n_) * 64 + scs8],                              \
                         &sAB[16384 + dst + wid * 2048 + i * 512 + lane * 8]);\
        }                                                                     \
    }

#define OKLOOP(A_, Bt_)                                                       \
    OSTAGE8(A_, Bt_, 0)                                                       \
    for (int n = 0; n < 16; ++n) {                                            \
        if (n + 1 < 16) {                                                     \
            OSTAGE8(A_, Bt_, n + 1)                                           \
            asm volatile("s_waitcnt vmcnt(8)" ::: "memory");                  \
        } else {                                                              \
            asm volatile("s_waitcnt vmcnt(0)" ::: "memory");                  \
        }                                                                     \
        __builtin_amdgcn_s_barrier();                                         \
        asm volatile("" ::: "memory");                                        \
        const int buf = (n & 1) * 8192;                                       \
        const u16* Ab = &sAB[buf + (wr * 64 + l15) * 64];                     \
        const u16* Bb = &sAB[16384 + buf + (wc * 64 + l15) * 64];             \
        bf16x8 a0[4], b0[4], a1[4], b1[4];                                    \
        _Pragma("unroll")                                                     \
        for (int mi = 0; mi < 4; mi++)                                        \
            a0[mi] = *(const bf16x8*)&Ab[mi * 1024 + sw0];                    \
        _Pragma("unroll")                                                     \
        for (int nj = 0; nj < 4; nj++)                                        \
            b0[nj] = *(const bf16x8*)&Bb[nj * 1024 + sw0];                    \
        __builtin_amdgcn_sched_barrier(0);                                    \
        _Pragma("unroll")                                                     \
        for (int mi = 0; mi < 4; mi++)                                        \
            a1[mi] = *(const bf16x8*)&Ab[mi * 1024 + sw1];                    \
        _Pragma("unroll")                                                     \
        for (int nj = 0; nj < 4; nj++)                                        \
            b1[nj] = *(const bf16x8*)&Bb[nj * 1024 + sw1];                    \
        asm volatile("s_waitcnt lgkmcnt(8)" ::: "memory");                    \
        __builtin_amdgcn_sched_barrier(0);                                    \
        MFMA16(a0, b0)                                                        \
        asm volatile("s_waitcnt lgkmcnt(0)" ::: "memory");                    \
        __builtin_amdgcn_sched_barrier(0);                                    \
        MFMA16(a1, b1)                                                        \
        __builtin_amdgcn_sched_barrier(0);                                    \
        asm volatile("" ::: "memory");                                        \
        __builtin_amdgcn_s_barrier();                                         \
    }

// bijective XCD swizzle (nwg % 8 == 0 for both GEMM grids)
#define XCD_SWIZZLE(BM_, BN_)                                                 \
    const int nwg = gridDim.x * gridDim.y;                                    \
    int orig = blockIdx.y * gridDim.x + blockIdx.x;                           \
    int wg = (orig & 7) * (nwg >> 3) + (orig >> 3);                           \
    const int bm = (wg / gridDim.x) * (BM_), bn = (wg % gridDim.x) * (BN_);

// ---------------------------------------------------------------------------
// QKV GEMM with fused rope+elu+mask epilogue -> bf16 head-major qb/kb/vb.
// grid (24, 32) = 768 blocks = 3.0 perfect rounds at 1 block/CU.
__global__ __launch_bounds__(512, 2) void gemm_qkv_kernel(
    const u16* __restrict__ A, const u16* __restrict__ Bt,
    const float* __restrict__ bias, const float* __restrict__ mask,
    const float* __restrict__ cosT, const float* __restrict__ sinT,
    u16* __restrict__ qb, u16* __restrict__ kb, u16* __restrict__ vb) {
    __shared__ u16 sAB[73728];                 // 144 KiB, triple-buffered
    const int tid  = threadIdx.x;
    const int wid  = tid >> 6, lane = tid & 63;
    const int wr = wid >> 1, wc = wid & 1;
    const int l15 = lane & 15, quad = lane >> 4;
    const int ln8 = lane >> 3;
    const int scs8 = ((lane & 7) ^ ln8) * 8;
    const int sw0 = (quad ^ (l15 & 7)) * 8;
    const int sw1 = ((4 + quad) ^ (l15 & 7)) * 8;
    XCD_SWIZZLE(256, 128)

    f32x4 acc[4][4];
#pragma unroll
    for (int i = 0; i < 4; i++)
#pragma unroll
        for (int j = 0; j < 4; j++) acc[i][j] = {0.f, 0.f, 0.f, 0.f};

    KLOOP(A, Bt)

    // ---- fused epilogue
    const int colbase = bn + wc * 64;          // multiple of 64
    const int region  = colbase >> 10;         // 0=q 1=k 2=v
    const int nh      = (colbase & 1023) >> 6;
    float bc[4];
#pragma unroll
    for (int nj = 0; nj < 4; nj++) bc[nj] = bias[colbase + nj * 16 + l15];
    u16* outp = (region == 0) ? qb : (region == 1) ? kb : vb;

#pragma unroll
    for (int mi = 0; mi < 4; mi++) {
#pragma unroll
        for (int r = 0; r < 4; r++) {
            int row = bm + wr * 64 + mi * 16 + quad * 4 + r;
            int b = row >> 11, s = row & (S_ - 1);
            size_t obase = ((size_t)(b * 16 + nh) * S_ + s) * 64;
            if (region < 2) {
                float mfac = (region == 0) ? 0.125f : mask[row];
#pragma unroll
                for (int p = 0; p < 2; p++) {
                    int d1 = p * 16 + l15;
                    float c  = cosT[s * 32 + d1];
                    float sn = sinT[s * 32 + d1];
                    float x1 = acc[mi][p][r]     + bc[p];
                    float x2 = acc[mi][p + 2][r] + bc[p + 2];
                    float r1 = x1 * c - x2 * sn;
                    float r2 = x2 * c + x1 * sn;
                    outp[obase + d1]      = f2bf(elu_k(r1) * mfac);
                    outp[obase + d1 + 32] = f2bf(elu_k(r2) * mfac);
                }
            } else {
                float mfac = mask[row];
#pragma unroll
                for (int nj = 0; nj < 4; nj++)
                    outp[obase + nj * 16 + l15] =
                        f2bf((acc[mi][nj][r] + bc[nj]) * mfac);
            }
        }
    }
}

// ---------------------------------------------------------------------------
// Output projection GEMM: C fp32 = A @ Bt^T + bias.  Unchanged.
__global__ __launch_bounds__(256, 2) void gemm_out_kernel(
    const u16* __restrict__ A, const u16* __restrict__ Bt,
    const float* __restrict__ bias, float* __restrict__ C, int N) {
    __shared__ u16 sAB[32768];                 // 64 KiB
    const int tid  = threadIdx.x;
    const int wid  = tid >> 6, lane = tid & 63;
    const int wr = wid >> 1, wc = wid & 1;
    const int l15 = lane & 15, quad = lane >> 4;
    const int ln8 = lane >> 3;
    const int scs8 = ((lane & 7) ^ ln8) * 8;
    const int sw0 = (quad ^ (l15 & 7)) * 8;
    const int sw1 = ((4 + quad) ^ (l15 & 7)) * 8;
    XCD_SWIZZLE(128, 128)

    f32x4 acc[4][4];
#pragma unroll
    for (int i = 0; i < 4; i++)
#pragma unroll
        for (int j = 0; j < 4; j++) acc[i][j] = {0.f, 0.f, 0.f, 0.f};

    OKLOOP(A, Bt)

#pragma unroll
    for (int mi = 0; mi < 4; mi++) {
#pragma unroll
        for (int nj = 0; nj < 4; nj++) {
            int col = bn + wc * 64 + nj * 16 + l15;
            float bcol = bias[col];
#pragma unroll
            for (int r = 0; r < 4; r++) {
                int row = bm + wr * 64 + mi * 16 + quad * 4 + r;
                C[(size_t)row * N + col] = acc[mi][nj][r] + bcol;
            }
        }
    }
}

// ---------------------------------------------------------------------------
// kv_part v2: grid (64 bn, NCH=8 chunks of 256 rows), 256 thr = 4 waves.
// Each wave owns a 64-row s-slice: stages its K/V rows as RAW bf16 into its
// private LDS region (no barrier needed -- per-wave regions), then 8x8
// per-thread tiles: per s, 2x ds_read_b128 (8+8 bf16) -> unpack -> 64 FMA.
// LDS reads/FLOP is 4x better than v1's 16x16x(4x4) layout.  One barrier,
// then in-LDS cross-wave reduce (strided, conflict-free) -> kvpart/kspart.
__global__ __launch_bounds__(256) void kv_part_kernel(
    const u16* __restrict__ kb, const u16* __restrict__ vb,
    float* __restrict__ kvpart, float* __restrict__ kspart) {
    __shared__ __align__(16) u16 sbuf[32768];   // 64 KiB: 4 x (ks 8KB | vs 8KB)
    __shared__ float ksred[256];
    const int bn  = blockIdx.x;
    const int s0  = blockIdx.y * 256;
    const int tid = threadIdx.x;
    const int sg  = tid >> 6;                   // wave id = s-slice
    const int lane = tid & 63;
    const int ti = lane >> 3, tj = lane & 7;    // 8x8 thread grid

    u16* ks = &sbuf[sg * 8192];                 // [64 s][64 d] bf16
    u16* vs = ks + 4096;

    const u16* kg = kb + (size_t)bn * (S_ * 64) + (size_t)(s0 + sg * 64) * 64;
    const u16* vg = vb + (size_t)bn * (S_ * 64) + (size_t)(s0 + sg * 64) * 64;
#pragma unroll
    for (int i = 0; i < 8; i++) {
        int off = (lane + i * 64) * 8;          // 512 chunks of 8 u16
        *(uint4*)&ks[off] = *(const uint4*)&kg[off];
        *(uint4*)&vs[off] = *(const uint4*)&vg[off];
    }
    // no barrier: each wave reads only its own region (compiler inserts
    // the lgkmcnt for the store->load dependency within the wave).

    float acc[8][8] = {};
    float ksacc = 0.f;
    for (int s = 0; s < 64; ++s) {
        uint4 ar = *(const uint4*)&ks[s * 64 + ti * 8];
        uint4 br = *(const uint4*)&vs[s * 64 + tj * 8];
        float a[8], b[8];
        a[0] = bfl(ar.x); a[1] = bfh(ar.x); a[2] = bfl(ar.y); a[3] = bfh(ar.y);
        a[4] = bfl(ar.z); a[5] = bfh(ar.z); a[6] = bfl(ar.w); a[7] = bfh(ar.w);
        b[0] = bfl(br.x); b[1] = bfh(br.x); b[2] = bfl(br.y); b[3] = bfh(br.y);
        b[4] = bfl(br.z); b[5] = bfh(br.z); b[6] = bfl(br.w); b[7] = bfh(br.w);
#pragma unroll
        for (int i = 0; i < 8; i++)
#pragma unroll
            for (int j = 0; j < 8; j++)
                acc[i][j] = fmaf(a[i], b[j], acc[i][j]);
        ksacc += bfu16(ks[s * 64 + lane]);      // column-sum, lane = d
    }

    // cross-wave reduce: reuse sbuf as float kvred[4][64][64] (each wave
    // overwrites only its OWN staging region; data already consumed).
    float* kvred = (float*)sbuf;
#pragma unroll
    for (int i = 0; i < 8; i++) {
        float4 lo = {acc[i][0], acc[i][1], acc[i][2], acc[i][3]};
        float4 hi = {acc[i][4], acc[i][5], acc[i][6], acc[i][7]};
        *(float4*)&kvred[sg * 4096 + (ti * 8 + i) * 64 + tj * 8 + 0] = lo;
        *(float4*)&kvred[sg * 4096 + (ti * 8 + i) * 64 + tj * 8 + 4] = hi;
    }
    ksred[sg * 64 + lane] = ksacc;
    __syncthreads();

    size_t obase = ((size_t)blockIdx.y * 64 + bn) * 4096;
#pragma unroll
    for (int w = 0; w < 16; w++) {
        int e = tid + w * 256;                  // strided: conflict-free b32
        float s = kvred[e] + kvred[4096 + e] + kvred[8192 + e]
                + kvred[12288 + e];
        kvpart[obase + e] = s;
    }
    if (tid < 64)
        kspart[((size_t)blockIdx.y * 64 + bn) * 64 + tid] =
            ksred[tid] + ksred[64 + tid] + ksred[128 + tid] + ksred[192 + tid];
}

// sum NCH=8 partials for kv (262144) and ksum (4096) in one launch
__global__ __launch_bounds__(256) void reduce_part_kernel(
    const float* __restrict__ kvpart, const float* __restrict__ kspart,
    float* __restrict__ kvb, float* __restrict__ ksum) {
    int i = blockIdx.x * 256 + threadIdx.x;
    if (i < 262144) {
        float s = 0.f;
#pragma unroll
        for (int c = 0; c < NCH; c++) s += kvpart[(size_t)c * 262144 + i];
        kvb[i] = s;
    } else if (i < 262144 + 4096) {
        int j = i - 262144;
        float s = 0.f;
#pragma unroll
        for (int c = 0; c < NCH; c++) s += kspart[(size_t)c * 4096 + j];
        ksum[j] = s;
    }
}

// ---------------------------------------------------------------------------
// MFMA combine: per (b,n), num = Q[256x64] @ kv[64x64], den via ksum column.
__global__ __launch_bounds__(256) void combine_kernel(
    const u16* __restrict__ qb, const float* __restrict__ kvb,
    const float* __restrict__ ksum, const float* __restrict__ g,
    const float* __restrict__ coeffp, u16* __restrict__ cmb) {
    int bn = blockIdx.x;
    int b = bn >> 4, n = bn & 15;
    __shared__ u16 qs[256 * 72];
    __shared__ u16 kvT[64 * 72];
    __shared__ u16 ksl[128];
    int tid = threadIdx.x;
    int s0 = blockIdx.y * 256;

    const u16* qsrc = qb + (size_t)bn * (S_ * 64) + (size_t)s0 * 64;
    for (int c = tid; c < 2048; c += 256) {
        int t = c >> 3, k8 = (c & 7) * 8;
        float4 tmp = *(const float4*)(qsrc + (size_t)c * 8);
        *(float4*)&qs[t * 72 + k8] = tmp;
    }
    for (int c = tid; c < 1024; c += 256) {
        int i = c >> 4, d4 = (c & 15) * 4;
        float4 kvv = *(const float4*)&kvb[(size_t)bn * 4096 + i * 64 + d4];
        kvT[(d4 + 0) * 72 + i] = f2bf(kvv.x);
        kvT[(d4 + 1) * 72 + i] = f2bf(kvv.y);
        kvT[(d4 + 2) * 72 + i] = f2bf(kvv.z);
        kvT[(d4 + 3) * 72 + i] = f2bf(kvv.w);
    }
    if (tid < 64)        ksl[tid] = f2bf(ksum[bn * 64 + tid]);
    else if (tid < 128)  ksl[tid] = 0;
    __syncthreads();

    int wave = tid >> 6, lane = tid & 63;
    int l15 = lane & 15, quad = lane >> 4;
    int wt = wave * 64;

    int ko0 = (l15 == 0) ? quad * 8      : 64;
    int ko1 = (l15 == 0) ? 32 + quad * 8 : 64;
    bf16x8 ksf0 = *(const bf16x8*)&ksl[ko0];
    bf16x8 ksf1 = *(const bf16x8*)&ksl[ko1];

    bf16x8 bfr0[4], bfr1[4];
#pragma unroll
    for (int nj = 0; nj < 4; nj++) {
        bfr0[nj] = *(const bf16x8*)&kvT[(nj * 16 + l15) * 72 + quad * 8];
        bfr1[nj] = *(const bf16x8*)&kvT[(nj * 16 + l15) * 72 + 32 + quad * 8];
    }

    f32x4 acc[4][4], dacc[4];
#pragma unroll
    for (int i = 0; i < 4; i++) {
        dacc[i] = {0.f, 0.f, 0.f, 0.f};
#pragma unroll
        for (int j = 0; j < 4; j++) acc[i][j] = {0.f, 0.f, 0.f, 0.f};
    }

#pragma unroll
    for (int mi = 0; mi < 4; mi++) {
        bf16x8 a0 = *(const bf16x8*)&qs[(wt + mi * 16 + l15) * 72 + quad * 8];
        bf16x8 a1 = *(const bf16x8*)&qs[(wt + mi * 16 + l15) * 72 + 32 + quad * 8];
        dacc[mi] = __builtin_amdgcn_mfma_f32_16x16x32_bf16(a0, ksf0, dacc[mi], 0, 0, 0);
        dacc[mi] = __builtin_amdgcn_mfma_f32_16x16x32_bf16(a1, ksf1, dacc[mi], 0, 0, 0);
#pragma unroll
        for (int nj = 0; nj < 4; nj++) {
            acc[mi][nj] = __builtin_amdgcn_mfma_f32_16x16x32_bf16(
                a0, bfr0[nj], acc[mi][nj], 0, 0, 0);
            acc[mi][nj] = __builtin_amdgcn_mfma_f32_16x16x32_bf16(
                a1, bfr1[nj], acc[mi][nj], 0, 0, 0);
        }
    }

    float coeff = *coeffp;
#pragma unroll
    for (int mi = 0; mi < 4; mi++) {
#pragma unroll
        for (int r = 0; r < 4; r++) {
            int s = s0 + wt + mi * 16 + quad * 4 + r;
            int t = b * S_ + s;
            float den = __shfl(dacc[mi][r], lane & 48) + 1e-6f;
            float gv = g[t];
            float w1 = gv / den + (1.f - gv) * coeff;
#pragma unroll
            for (int nj = 0; nj < 4; nj++) {
                int d = nj * 16 + l15;
                cmb[(size_t)t * H_ + n * 64 + d] = f2bf(acc[mi][nj][r] * w1);
            }
        }
    }
}

// ---------------------------------------------------------------------------
extern "C" void kernel_launch(void* const* d_in, const int* in_sizes, int n_in,
                              void* d_out, int out_size, void* d_ws, size_t ws_size,
                              hipStream_t stream) {
    const float* hs    = (const float*)d_in[0];
    const float* mask  = (const float*)d_in[1];
    const float* Wq    = (const float*)d_in[2];
    const float* bq    = (const float*)d_in[3];
    const float* Wk    = (const float*)d_in[4];
    const float* bk    = (const float*)d_in[5];
    const float* Wv    = (const float*)d_in[6];
    const float* bv    = (const float*)d_in[7];
    const float* Wo    = (const float*)d_in[8];
    const float* bo    = (const float*)d_in[9];
    const float* Wg    = (const float*)d_in[10];
    const float* bg    = (const float*)d_in[11];
    const float* decay = (const float*)d_in[12];
    const float* gate  = (const float*)d_in[13];
    float* out = (float*)d_out;

    // ---- workspace layout
    float* ws     = (float*)d_ws;
    float* kvb    = ws;                         // 262144
    float* ksum   = kvb + 262144;               // 4096
    float* gbuf   = ksum + 4096;                // 8192
    float* coeff  = gbuf + 8192;                // 64
    float* cosT   = coeff + 64;                 // 65536
    float* sinT   = cosT + 65536;               // 65536
    float* bqkv   = sinT + 65536;               // 3072 (+pad to 4096)
    float* kspart = bqkv + 4096;                // NCH*4096 <= 65536
    float* kvpart = kspart + 65536;             // NCH*262144 <= 4194304
    u16*   hsb    = (u16*)(kvpart + 4194304);   // T*1024
    u16*   Wt     = hsb + (size_t)T_ * H_;      // 4096*1024
    u16*   WoT    = Wt + (size_t)3072 * H_;
    u16*   qb     = Wt + (size_t)4096 * H_;     // T*1024 head-major
    u16*   kb     = qb + (size_t)T_ * H_;
    u16*   vb     = kb + (size_t)T_ * H_;
    u16*   cmb    = vb + (size_t)T_ * H_;

    pre_kernel<<<T_ + 1024 + 270, 256, 0, stream>>>(
        hs, Wg, bg, Wq, Wk, Wv, Wo, decay, gate, bq, bk, bv,
        hsb, gbuf, Wt, coeff, cosT, sinT, bqkv);

    gemm_qkv_kernel<<<dim3(3072 / 128, T_ / 256), 512, 0, stream>>>(
        hsb, Wt, bqkv, mask, cosT, sinT, qb, kb, vb);

    kv_part_kernel<<<dim3(B_ * NH, NCH), 256, 0, stream>>>(
        kb, vb, kvpart, kspart);
    reduce_part_kernel<<<(262144 + 4096 + 255) / 256, 256, 0, stream>>>(
        kvpart, kspart, kvb, ksum);

    combine_kernel<<<dim3(B_ * NH, S_ / 256), 256, 0, stream>>>(
        qb, kvb, ksum, gbuf, coeff, cmb);

    gemm_out_kernel<<<dim3(H_ / 128, T_ / 128), 256, 0, stream>>>(
        cmb, WoT, bo, out, H_);
}